// Round 1
// baseline (187.010 us; speedup 1.0000x reference)
//
#include <hip/hip_runtime.h>
#include <math.h>

// MultiBoxLoss (SSD) on MI355X.
// R7: 6 dispatches -> 2. The 3-level radix select (previously k_h2/k_h3/k_neg
// with global histograms + kernel boundaries between levels) now runs in ONE
// block per batch row: 1024 threads hold the row's 65536 keys in VGPRs
// (64/thread) and the 11/10/10-bit histograms live in LDS, so level
// boundaries are __syncthreads instead of dispatch boundaries.
// k_init is gone: pos partials are plain stores to distinct slots (no atomics,
// no zeroing), row_np is recomputed from slot partials, eq-tie counter is LDS.
// k_final is fused into k_select via a last-block-done acq_rel counter.

#define MAXB 64
#define NSLOT 1024  // = (A/4096) * B = 16 * 64

struct Accum {
  float f_loc[NSLOT], f_clsp[NSLOT], f_perr[NSLOT], f_se0[NSLOT], f_se1[NSLOT];
  int i_pcor[NSLOT], i_pcnt[NSLOT];
  // final accumulators (zeroed by k_main slot-0 block, coherent at boundary)
  float f_clsn;
  unsigned int i_ncor, i_ntot, done;
};

__device__ __forceinline__ float iou_f(float4 g, float4 an) {
  float ax0 = an.x - an.z * 0.5f, ay0 = an.y - an.w * 0.5f;
  float ax1 = an.x + an.z * 0.5f, ay1 = an.y + an.w * 0.5f;
  float ltx = fmaxf(g.x, ax0), lty = fmaxf(g.y, ay0);
  float rbx = fminf(g.z, ax1), rby = fminf(g.w, ay1);
  float w = fmaxf(rbx - ltx, 0.f), h = fmaxf(rby - lty, 0.f);
  float inter = w * h;
  float area_g = (g.z - g.x) * (g.w - g.y);
  float area_a = (ax1 - ax0) * (ay1 - ay0);
  return inter / (area_g + area_a - inter);
}

__device__ __forceinline__ float sl1(float x) {
  float ax = fabsf(x);
  return ax < 1.f ? 0.5f * x * x : ax - 0.5f;
}

// keys + positive losses. grid (A/4096, B), 256 threads.
__global__ __launch_bounds__(256) void k_main(
    const float* __restrict__ loc_pred, const float* __restrict__ conf,
    const float* __restrict__ gt, const float* __restrict__ anchors,
    Accum* __restrict__ acc, unsigned int* __restrict__ keys, int A) {
  int b = blockIdx.y;
  int tid = threadIdx.x;
  int lane = tid & 63, wv = tid >> 6;
  __shared__ float smf[5][4];
  __shared__ int smi[2][4];

  float4 g4 = reinterpret_cast<const float4*>(gt)[b];
  const float4* conf4 = reinterpret_cast<const float4*>(conf);
  const float4* anc4 = reinterpret_cast<const float4*>(anchors);
  const float4* loc4 = reinterpret_cast<const float4*>(loc_pred);
  int abase = blockIdx.x * 4096;
  long long cbase = ((long long)b * A + abase) >> 1;  // float4 units
  uint2* keys2 = reinterpret_cast<uint2*>(keys);

  float loc_s = 0.f, clsp = 0.f, perr = 0.f, se0 = 0.f, se1 = 0.f;
  int pcnt = 0, pcor = 0;

#pragma unroll
  for (int j = 0; j < 8; ++j) {
    float4 cc = conf4[cbase + tid + j * 256];
    int a0 = abase + 2 * (tid + j * 256);
    uint2 kv;
#pragma unroll
    for (int h = 0; h < 2; ++h) {
      int a = a0 + h;
      float c0 = h ? cc.z : cc.x;
      float c1 = h ? cc.w : cc.y;
      float4 an = anc4[a];
      float ov = iou_f(g4, an);
      unsigned int kk = 0u;
      if (ov <= 0.3f) {
        float m = fmaxf(c0, c1);
        float s = logf(expf(c0 - m) + expf(c1 - m));
        kk = __float_as_uint((m - c0) + s);
      }
      if (c1 > c0) kk |= 0x80000000u;
      if (h) kv.y = kk; else kv.x = kk;
      if (ov >= 0.6f) {
        float4 lp = loc4[(long long)b * A + a];
        float gcx = (g4.x + g4.z) * 0.5f, gcy = (g4.y + g4.w) * 0.5f;
        float gw = g4.z - g4.x, gh = g4.w - g4.y;
        float t0 = (gcx - an.x) / (0.1f * an.z);
        float t1 = (gcy - an.y) / (0.1f * an.w);
        float t2 = logf(gw / an.z) / 0.2f;
        float t3 = logf(gh / an.w) / 0.2f;
        loc_s += sl1(lp.x - t0) + sl1(lp.y - t1) + sl1(lp.z - t2) +
                 sl1(lp.w - t3);
        float m = fmaxf(c0, c1);
        float s = logf(expf(c0 - m) + expf(c1 - m));
        clsp += (m - c1) + s;
        pcnt += 1;
        pcor += (c1 > c0) ? 1 : 0;
        float dcx = an.x + lp.x * 0.1f * an.z;
        float dcy = an.y + lp.y * 0.1f * an.w;
        float dw = an.z * expf(lp.z * 0.2f);
        float dh = an.w * expf(lp.w * 0.2f);
        float dx0 = dcx - dw * 0.5f, dy0 = dcy - dh * 0.5f;
        float ex = (g4.x - dx0) * 255.f, ey = (g4.y - dy0) * 255.f;
        perr += sqrtf(ex * ex + ey * ey);
        se0 += fabsf(g4.z - (dx0 + dw));
        se1 += fabsf(g4.w - (dy0 + dh));
      }
    }
    keys2[cbase + tid + j * 256] = kv;
  }

  // block-reduce positive stats -> plain stores to this block's unique slot
  float fv[5] = {loc_s, clsp, perr, se0, se1};
  int iv[2] = {pcnt, pcor};
#pragma unroll
  for (int q = 0; q < 5; ++q) {
    float v = fv[q];
#pragma unroll
    for (int o = 32; o > 0; o >>= 1) v += __shfl_down(v, o, 64);
    if (lane == 0) smf[q][wv] = v;
  }
#pragma unroll
  for (int q = 0; q < 2; ++q) {
    int v = iv[q];
#pragma unroll
    for (int o = 32; o > 0; o >>= 1) v += __shfl_down(v, o, 64);
    if (lane == 0) smi[q][wv] = v;
  }
  __syncthreads();
  if (tid == 0) {
    float L = 0, C = 0, P = 0, S0 = 0, S1 = 0;
    int PC = 0, COR = 0;
    for (int w2 = 0; w2 < 4; ++w2) {
      L += smf[0][w2]; C += smf[1][w2]; P += smf[2][w2];
      S0 += smf[3][w2]; S1 += smf[4][w2];
      PC += smi[0][w2]; COR += smi[1][w2];
    }
    int slot = b * gridDim.x + blockIdx.x;
    acc->f_loc[slot] = L;
    acc->f_clsp[slot] = C;
    acc->f_perr[slot] = P;
    acc->f_se0[slot] = S0;
    acc->f_se1[slot] = S1;
    acc->i_pcor[slot] = COR;
    acc->i_pcnt[slot] = PC;
    if (slot == 0) {
      acc->f_clsn = 0.f;
      acc->i_ncor = 0u;
      acc->i_ntot = 0u;
      acc->done = 0u;
    }
  }
}

// Block-wide pick over an LDS histogram whose per-thread local counts are in
// cnt[PER] (thread t owns bins [t*PER, t*PER+PER)). Finds the bin where the
// from-the-top cumulative count crosses kr_in; returns (bin, residual rank).
template <int NB>
__device__ __forceinline__ uint2 pick1024(const unsigned int* cnt, int kr_in,
                                          unsigned int* s_wsum,
                                          unsigned int* s_bin,
                                          unsigned int* s_kr) {
  const int tid = threadIdx.x, lane = tid & 63, wv = tid >> 6;
  constexpr int PER = NB / 1024;
  unsigned int my = 0;
#pragma unroll
  for (int i = 0; i < PER; ++i) my += cnt[i];
  // suffix-inclusive scan within wave (higher lane = higher bins)
  unsigned int v = my;
#pragma unroll
  for (int o = 1; o < 64; o <<= 1) {
    unsigned int tv = __shfl_down(v, o, 64);
    if (lane + o < 64) v += tv;
  }
  if (lane == 0) s_wsum[wv] = v;
  __syncthreads();
  unsigned int off = 0;
#pragma unroll
  for (int w2 = 0; w2 < 16; ++w2)
    if (w2 > wv) off += s_wsum[w2];
  unsigned int incl = v + off;
  unsigned int above = incl - my;
  if ((int)above < kr_in && kr_in <= (int)incl) {
    int kk = kr_in - (int)above;
#pragma unroll
    for (int i = PER - 1; i >= 0; --i) {
      int c = (int)cnt[i];
      if (kk <= c) {
        *s_bin = (unsigned int)(tid * PER + i);
        *s_kr = (unsigned int)kk;
        break;
      }
      kk -= c;
    }
  }
  __syncthreads();
  uint2 r;
  r.x = *s_bin;
  r.y = *s_kr;
  __syncthreads();  // protect s_bin/s_kr/s_wsum reuse by the next pick
  return r;
}

// One block per batch row: 3-level radix select + negative accumulation +
// (last block only) the global final reduction. 1024 threads, keys in VGPRs.
__global__ __launch_bounds__(1024) void k_select(
    const unsigned int* __restrict__ keys, Accum* __restrict__ acc,
    float* __restrict__ out, int A, int spr) {
  int b = blockIdx.x;
  int tid = threadIdx.x;
  int lane = tid & 63, wv = tid >> 6;
  __shared__ unsigned int h1[4][2048];  // bits [30:20], replica per 4 waves
  __shared__ unsigned int h2[1024];     // bits [19:10]
  __shared__ unsigned int h3[1024];     // bits [9:0]
  __shared__ unsigned int s_wsum[16];
  __shared__ unsigned int s_bin, s_kr;
  __shared__ int s_npar[16];
  __shared__ unsigned int s_eq;
  __shared__ unsigned int s_lastf;
  __shared__ float s_nf[16];
  __shared__ int s_ni[2][16];
  __shared__ float s_rf[5][16];
  __shared__ int s_ri[2][16];

  // zero all hists upfront (one barrier covers everything)
  unsigned int* hz = &h1[0][0];
#pragma unroll
  for (int i = 0; i < 8; ++i) hz[tid + i * 1024] = 0u;
  h2[tid] = 0u;
  h3[tid] = 0u;
  if (tid < spr) s_npar[tid] = acc->i_pcnt[b * spr + tid];
  if (tid == 0) s_eq = 0u;

  // load this row's 65536 keys into registers (64 per thread, coalesced)
  unsigned int kk[64];
  const uint4* k4 = reinterpret_cast<const uint4*>(keys);
  long long base4 = ((long long)b * A) >> 2;
#pragma unroll
  for (int j = 0; j < 16; ++j) {
    uint4 v = k4[base4 + tid + j * 1024];
    kk[4 * j + 0] = v.x; kk[4 * j + 1] = v.y;
    kk[4 * j + 2] = v.z; kk[4 * j + 3] = v.w;
  }
  __syncthreads();

  int np = 0;
#pragma unroll
  for (int i = 0; i < 16; ++i) np += (i < spr) ? s_npar[i] : 0;
  int k = 3 * np;
  if (k < 10) k = 10;
  if (k > A - 1) k = A - 1;

  // level 1: 11-bit hist of bits [30:20]
  unsigned int* hw = h1[wv >> 2];
#pragma unroll
  for (int j = 0; j < 64; ++j)
    atomicAdd(&hw[(kk[j] & 0x7FFFFFFFu) >> 20], 1u);
  __syncthreads();
  unsigned int c1l[2];
#pragma unroll
  for (int i = 0; i < 2; ++i) {
    int bin = 2 * tid + i;
    c1l[i] = h1[0][bin] + h1[1][bin] + h1[2][bin] + h1[3][bin];
  }
  uint2 p1 = pick1024<2048>(c1l, k, s_wsum, &s_bin, &s_kr);

  // level 2: 10-bit hist of bits [19:10] among keys in bin1
#pragma unroll
  for (int j = 0; j < 64; ++j) {
    unsigned int k31 = kk[j] & 0x7FFFFFFFu;
    if ((k31 >> 20) == p1.x) atomicAdd(&h2[(k31 >> 10) & 0x3FFu], 1u);
  }
  __syncthreads();
  unsigned int c2l = h2[tid];
  uint2 p2 = pick1024<1024>(&c2l, (int)p1.y, s_wsum, &s_bin, &s_kr);

  // level 3: 10-bit hist of bits [9:0] among keys matching bins 1+2
  unsigned int pref21 = (p1.x << 10) | p2.x;
#pragma unroll
  for (int j = 0; j < 64; ++j) {
    unsigned int k31 = kk[j] & 0x7FFFFFFFu;
    if ((k31 >> 10) == pref21) atomicAdd(&h3[k31 & 0x3FFu], 1u);
  }
  __syncthreads();
  unsigned int c3l = h3[tid];
  uint2 p3 = pick1024<1024>(&c3l, (int)p2.y, s_wsum, &s_bin, &s_kr);

  unsigned int thr = (pref21 << 10) | p3.x;
  int need = (int)p3.y;

  // selection + accumulation
  float cls = 0.f;
  int ncnt = 0, ncor = 0;
#pragma unroll
  for (int j = 0; j < 64; ++j) {
    unsigned int k31 = kk[j] & 0x7FFFFFFFu;
    bool s = false;
    if (k31 > thr) {
      s = true;
    } else if (k31 == thr) {
      unsigned int ord = atomicAdd(&s_eq, 1u);
      if ((int)ord < need) s = true;
    }
    if (s) {
      cls += __uint_as_float(k31);
      ncnt += 1;
      ncor += (int)((kk[j] >> 31) ^ 1u);
    }
  }
  {
    float v = cls;
#pragma unroll
    for (int o = 32; o > 0; o >>= 1) v += __shfl_down(v, o, 64);
    if (lane == 0) s_nf[wv] = v;
  }
  {
    int v = ncnt;
#pragma unroll
    for (int o = 32; o > 0; o >>= 1) v += __shfl_down(v, o, 64);
    if (lane == 0) s_ni[0][wv] = v;
  }
  {
    int v = ncor;
#pragma unroll
    for (int o = 32; o > 0; o >>= 1) v += __shfl_down(v, o, 64);
    if (lane == 0) s_ni[1][wv] = v;
  }
  __syncthreads();
  if (tid == 0) {
    float C = 0;
    int NC = 0, COR = 0;
    for (int w2 = 0; w2 < 16; ++w2) {
      C += s_nf[w2];
      NC += s_ni[0][w2];
      COR += s_ni[1][w2];
    }
    atomicAdd(&acc->f_clsn, C);
    atomicAdd(&acc->i_ntot, (unsigned int)NC);
    atomicAdd(&acc->i_ncor, (unsigned int)COR);
  }

  // last-block-done final reduction
  __threadfence();  // release: our atomics above are ordered before the count
  if (tid == 0) {
    unsigned int old = __hip_atomic_fetch_add(&acc->done, 1u, __ATOMIC_ACQ_REL,
                                              __HIP_MEMORY_SCOPE_AGENT);
    s_lastf = (old == (unsigned int)(gridDim.x - 1)) ? 1u : 0u;
  }
  __syncthreads();
  if (s_lastf) {
    __threadfence();  // acquire: make other blocks' atomics visible
    // pos partial slots were written by the previous kernel (coherent).
    float fv[5];
    int iv[2];
    fv[0] = acc->f_loc[tid];
    fv[1] = acc->f_clsp[tid];
    fv[2] = acc->f_perr[tid];
    fv[3] = acc->f_se0[tid];
    fv[4] = acc->f_se1[tid];
    iv[0] = acc->i_pcor[tid];
    iv[1] = acc->i_pcnt[tid];
#pragma unroll
    for (int q = 0; q < 5; ++q) {
      float v = fv[q];
#pragma unroll
      for (int o = 32; o > 0; o >>= 1) v += __shfl_down(v, o, 64);
      if (lane == 0) s_rf[q][wv] = v;
    }
#pragma unroll
    for (int q = 0; q < 2; ++q) {
      int v = iv[q];
#pragma unroll
      for (int o = 32; o > 0; o >>= 1) v += __shfl_down(v, o, 64);
      if (lane == 0) s_ri[q][wv] = v;
    }
    __syncthreads();
    if (tid == 0) {
      float T[5] = {0, 0, 0, 0, 0};
      int TI[2] = {0, 0};
      for (int w2 = 0; w2 < 16; ++w2) {
        T[0] += s_rf[0][w2]; T[1] += s_rf[1][w2]; T[2] += s_rf[2][w2];
        T[3] += s_rf[3][w2]; T[4] += s_rf[4][w2];
        TI[0] += s_ri[0][w2]; TI[1] += s_ri[1][w2];
      }
      float clsn = __hip_atomic_load(&acc->f_clsn, __ATOMIC_RELAXED,
                                     __HIP_MEMORY_SCOPE_AGENT);
      unsigned int ntot = __hip_atomic_load(&acc->i_ntot, __ATOMIC_RELAXED,
                                            __HIP_MEMORY_SCOPE_AGENT);
      unsigned int ncr = __hip_atomic_load(&acc->i_ncor, __ATOMIC_RELAXED,
                                           __HIP_MEMORY_SCOPE_AGENT);
      float N = (float)TI[1];
      float Nf = fmaxf(N, 1.f);
      out[0] = T[0] / (Nf * 4.f);
      float wsum = N + (float)ntot * (1.f / 3.f);
      out[1] = (T[1] + clsn * (1.f / 3.f)) / wsum;
      out[2] = (float)TI[0] / fmaxf(N, 1.f);
      out[3] = (float)ncr / fmaxf((float)ntot, 1.f);
      out[4] = T[2] / Nf;
      out[5] = T[3] / Nf * 255.f;
      out[6] = T[4] / Nf * 255.f;
      out[7] = N;
    }
  }
}

extern "C" void kernel_launch(void* const* d_in, const int* in_sizes, int n_in,
                              void* d_out, int out_size, void* d_ws,
                              size_t ws_size, hipStream_t stream) {
  (void)n_in; (void)out_size; (void)ws_size;
  const float* loc = (const float*)d_in[0];
  const float* conf = (const float*)d_in[1];
  const float* gt = (const float*)d_in[2];
  const float* anchors = (const float*)d_in[3];
  int B = in_sizes[2] / 4;  // 64
  int A = in_sizes[3] / 4;  // 65536
  float* out = (float*)d_out;

  char* w = (char*)d_ws;
  Accum* acc = (Accum*)w;
  size_t off = (sizeof(Accum) + 255) & ~(size_t)255;
  unsigned int* keys = (unsigned int*)(w + off);

  int spr = A / 4096;  // slots per row = 16
  dim3 grid(spr, B);
  k_main<<<grid, 256, 0, stream>>>(loc, conf, gt, anchors, acc, keys, A);
  k_select<<<B, 1024, 0, stream>>>(keys, acc, out, A, spr);
}

// Round 2
// 166.359 us; speedup vs baseline: 1.1241x; 1.1241x over previous
//
#include <hip/hip_runtime.h>
#include <math.h>

// MultiBoxLoss (SSD) on MI355X.
// R8: fix k_select (was 65us: VGPR_Count=64 => the 64-key register array
// spilled to scratch; 64 blocks, 9% occupancy, latency-bound).
// New select: k_main fuses a 256-bin exponent histogram (bits[30:23]) written
// non-atomically per (row, block) slice (no init dispatch). k_select makes ONE
// streaming pass over the row's keys: above-bin keys accumulate immediately
// (they are guaranteed-selected, ~k of them), in-bin keys (few hundred) go to
// an LDS candidate buffer; the remaining 23 key bits are radix-selected
// entirely in LDS. Rare >CAP bins fall back to a streaming refinement loop.
// Still exactly 2 dispatches; tie semantics identical to R7.

#define NB1 256
#define CAP 24576
#define NSLOT 1024  // = (A/4096) * B = 16 * 64

struct Accum {
  float f_loc[NSLOT], f_clsp[NSLOT], f_perr[NSLOT], f_se0[NSLOT], f_se1[NSLOT];
  int i_pcor[NSLOT], i_pcnt[NSLOT];
  // final accumulators (zeroed by k_main slot-0 block, coherent at boundary)
  float f_clsn;
  unsigned int i_ncor, i_ntot, done;
};

__device__ __forceinline__ float iou_f(float4 g, float4 an) {
  float ax0 = an.x - an.z * 0.5f, ay0 = an.y - an.w * 0.5f;
  float ax1 = an.x + an.z * 0.5f, ay1 = an.y + an.w * 0.5f;
  float ltx = fmaxf(g.x, ax0), lty = fmaxf(g.y, ay0);
  float rbx = fminf(g.z, ax1), rby = fminf(g.w, ay1);
  float w = fmaxf(rbx - ltx, 0.f), h = fmaxf(rby - lty, 0.f);
  float inter = w * h;
  float area_g = (g.z - g.x) * (g.w - g.y);
  float area_a = (ax1 - ax0) * (ay1 - ay0);
  return inter / (area_g + area_a - inter);
}

__device__ __forceinline__ float sl1(float x) {
  float ax = fabsf(x);
  return ax < 1.f ? 0.5f * x * x : ax - 0.5f;
}

// keys + positive losses + fused 256-bin hist slice. grid (A/4096, B).
__global__ __launch_bounds__(256) void k_main(
    const float* __restrict__ loc_pred, const float* __restrict__ conf,
    const float* __restrict__ gt, const float* __restrict__ anchors,
    Accum* __restrict__ acc, unsigned int* __restrict__ g1,
    unsigned int* __restrict__ keys, int A) {
  int b = blockIdx.y;
  int tid = threadIdx.x;
  int lane = tid & 63, wv = tid >> 6;
  __shared__ unsigned int hist[4][NB1];  // one replica per wave (4 KB)
  __shared__ float smf[5][4];
  __shared__ int smi[2][4];
  for (int i = tid; i < 4 * NB1; i += 256) ((unsigned int*)hist)[i] = 0u;
  __syncthreads();

  float4 g4 = reinterpret_cast<const float4*>(gt)[b];
  const float4* conf4 = reinterpret_cast<const float4*>(conf);
  const float4* anc4 = reinterpret_cast<const float4*>(anchors);
  const float4* loc4 = reinterpret_cast<const float4*>(loc_pred);
  int abase = blockIdx.x * 4096;
  long long cbase = ((long long)b * A + abase) >> 1;  // float4 units
  uint2* keys2 = reinterpret_cast<uint2*>(keys);

  float loc_s = 0.f, clsp = 0.f, perr = 0.f, se0 = 0.f, se1 = 0.f;
  int pcnt = 0, pcor = 0;

#pragma unroll
  for (int j = 0; j < 8; ++j) {
    float4 cc = conf4[cbase + tid + j * 256];
    int a0 = abase + 2 * (tid + j * 256);
    uint2 kv;
#pragma unroll
    for (int h = 0; h < 2; ++h) {
      int a = a0 + h;
      float c0 = h ? cc.z : cc.x;
      float c1 = h ? cc.w : cc.y;
      float4 an = anc4[a];
      float ov = iou_f(g4, an);
      unsigned int kk = 0u;
      if (ov <= 0.3f) {
        float m = fmaxf(c0, c1);
        float s = logf(expf(c0 - m) + expf(c1 - m));
        kk = __float_as_uint((m - c0) + s);
      }
      if (c1 > c0) kk |= 0x80000000u;
      if (h) kv.y = kk; else kv.x = kk;
      atomicAdd(&hist[wv][(kk & 0x7FFFFFFFu) >> 23], 1u);
      if (ov >= 0.6f) {
        float4 lp = loc4[(long long)b * A + a];
        float gcx = (g4.x + g4.z) * 0.5f, gcy = (g4.y + g4.w) * 0.5f;
        float gw = g4.z - g4.x, gh = g4.w - g4.y;
        float t0 = (gcx - an.x) / (0.1f * an.z);
        float t1 = (gcy - an.y) / (0.1f * an.w);
        float t2 = logf(gw / an.z) / 0.2f;
        float t3 = logf(gh / an.w) / 0.2f;
        loc_s += sl1(lp.x - t0) + sl1(lp.y - t1) + sl1(lp.z - t2) +
                 sl1(lp.w - t3);
        float m = fmaxf(c0, c1);
        float s = logf(expf(c0 - m) + expf(c1 - m));
        clsp += (m - c1) + s;
        pcnt += 1;
        pcor += (c1 > c0) ? 1 : 0;
        float dcx = an.x + lp.x * 0.1f * an.z;
        float dcy = an.y + lp.y * 0.1f * an.w;
        float dw = an.z * expf(lp.z * 0.2f);
        float dh = an.w * expf(lp.w * 0.2f);
        float dx0 = dcx - dw * 0.5f, dy0 = dcy - dh * 0.5f;
        float ex = (g4.x - dx0) * 255.f, ey = (g4.y - dy0) * 255.f;
        perr += sqrtf(ex * ex + ey * ey);
        se0 += fabsf(g4.z - (dx0 + dw));
        se1 += fabsf(g4.w - (dy0 + dh));
      }
    }
    keys2[cbase + tid + j * 256] = kv;
  }

  // wave-reduce positive stats (register shuffles, no LDS dependency yet)
  float fv[5] = {loc_s, clsp, perr, se0, se1};
  int iv[2] = {pcnt, pcor};
#pragma unroll
  for (int q = 0; q < 5; ++q) {
    float v = fv[q];
#pragma unroll
    for (int o = 32; o > 0; o >>= 1) v += __shfl_down(v, o, 64);
    if (lane == 0) smf[q][wv] = v;
  }
#pragma unroll
  for (int q = 0; q < 2; ++q) {
    int v = iv[q];
#pragma unroll
    for (int o = 32; o > 0; o >>= 1) v += __shfl_down(v, o, 64);
    if (lane == 0) smi[q][wv] = v;
  }
  __syncthreads();

  // flush hist slice (non-atomic: per-(row,block) region, no init needed)
  {
    int slot = b * gridDim.x + blockIdx.x;
    unsigned int* dst = g1 + (long long)slot * NB1;
    for (int i = tid; i < NB1; i += 256)
      dst[i] = hist[0][i] + hist[1][i] + hist[2][i] + hist[3][i];
  }

  if (tid == 0) {
    float L = 0, C = 0, P = 0, S0 = 0, S1 = 0;
    int PC = 0, COR = 0;
    for (int w2 = 0; w2 < 4; ++w2) {
      L += smf[0][w2]; C += smf[1][w2]; P += smf[2][w2];
      S0 += smf[3][w2]; S1 += smf[4][w2];
      PC += smi[0][w2]; COR += smi[1][w2];
    }
    int slot = b * gridDim.x + blockIdx.x;
    acc->f_loc[slot] = L;
    acc->f_clsp[slot] = C;
    acc->f_perr[slot] = P;
    acc->f_se0[slot] = S0;
    acc->f_se1[slot] = S1;
    acc->i_pcor[slot] = COR;
    acc->i_pcnt[slot] = PC;
    if (slot == 0) {
      acc->f_clsn = 0.f;
      acc->i_ncor = 0u;
      acc->i_ntot = 0u;
      acc->done = 0u;
    }
  }
}

// Block-wide pick over an LDS histogram of NB (<=1024) bins, one bin per
// thread (tid < NB). Finds the bin where the from-the-top cumulative count
// crosses kr; returns (bin, residual rank) to all threads.
__device__ uint2 pickB(const unsigned int* h, int NB, int kr,
                       unsigned int* s_wsum, unsigned int* s_bin,
                       unsigned int* s_kr) {
  const int tid = threadIdx.x, lane = tid & 63, wv = tid >> 6;
  unsigned int my = (tid < NB) ? h[tid] : 0u;
  unsigned int v = my;
#pragma unroll
  for (int o = 1; o < 64; o <<= 1) {
    unsigned int tv = __shfl_down(v, o, 64);
    if (lane + o < 64) v += tv;
  }
  if (lane == 0) s_wsum[wv] = v;
  __syncthreads();
  unsigned int off = 0;
#pragma unroll
  for (int w2 = 0; w2 < 16; ++w2)
    if (w2 > wv) off += s_wsum[w2];
  unsigned int incl = v + off;
  unsigned int above = incl - my;
  if ((int)above < kr && kr <= (int)incl) {
    *s_bin = (unsigned int)tid;
    *s_kr = (unsigned int)(kr - (int)above);
  }
  __syncthreads();
  uint2 r;
  r.x = *s_bin;
  r.y = *s_kr;
  __syncthreads();  // protect s_* reuse by the next pick
  return r;
}

// One block per batch row: streaming radix select + negative accumulation +
// (last block) the global final reduction. 1024 threads, keys NOT held.
__global__ __launch_bounds__(1024) void k_select(
    const unsigned int* __restrict__ keys, const unsigned int* __restrict__ g1,
    Accum* __restrict__ acc, float* __restrict__ out, int A, int spr) {
  int b = blockIdx.x;
  int tid = threadIdx.x;
  int lane = tid & 63, wv = tid >> 6;
  __shared__ unsigned int hist[1024];
  __shared__ unsigned int cand[CAP];  // 96 KB
  __shared__ unsigned int s_wsum[16];
  __shared__ unsigned int s_bin, s_kr;
  __shared__ unsigned int s_ccnt, s_eq;
  __shared__ int s_npar[16];
  __shared__ unsigned int s_lastf;
  __shared__ float s_nf[16];
  __shared__ int s_ni[2][16];
  __shared__ float s_rf[5][16];
  __shared__ int s_ri[2][16];

  // merge the spr per-block hist slices into one 256-bin row histogram
  if (tid < NB1) {
    unsigned int c = 0;
    const unsigned int* src = g1 + (long long)b * spr * NB1;
    for (int s = 0; s < spr; ++s) c += src[s * NB1 + tid];
    hist[tid] = c;
  }
  if (tid < spr) s_npar[tid] = acc->i_pcnt[b * spr + tid];
  if (tid == 0) {
    s_ccnt = 0u;
    s_eq = 0u;
  }
  __syncthreads();

  int np = 0;
  for (int i = 0; i < spr; ++i) np += s_npar[i];
  int k = 3 * np;
  if (k < 10) k = 10;
  if (k > A - 1) k = A - 1;

  uint2 p = pickB(hist, NB1, k, s_wsum, &s_bin, &s_kr);
  unsigned int prefix = p.x;
  int r = (int)p.y;
  int pbits = 8;
  unsigned int cbin = hist[prefix];

  const uint4* k4 = reinterpret_cast<const uint4*>(keys);
  long long base4 = ((long long)b * A) >> 2;

  // rare fallback: refine prefix by 10 bits/streaming pass until bin fits LDS
  while (cbin > CAP && pbits < 31) {
    int nb = 31 - pbits;
    if (nb > 10) nb = 10;
    int shN = 31 - pbits, sh2 = 31 - pbits - nb;
    unsigned int msk = (1u << nb) - 1u;
    hist[tid] = 0u;
    __syncthreads();
    for (int j = 0; j < 16; ++j) {
      uint4 v = k4[base4 + tid + j * 1024];
      unsigned int w4[4] = {v.x, v.y, v.z, v.w};
#pragma unroll
      for (int e = 0; e < 4; ++e) {
        unsigned int k31 = w4[e] & 0x7FFFFFFFu;
        if ((k31 >> shN) == prefix)
          atomicAdd(&hist[(k31 >> sh2) & msk], 1u);
      }
    }
    __syncthreads();
    p = pickB(hist, 1 << nb, r, s_wsum, &s_bin, &s_kr);
    prefix = (prefix << nb) | p.x;
    r = (int)p.y;
    pbits += nb;
    cbin = hist[p.x];
    __syncthreads();
  }

  float cls = 0.f;
  int ncnt = 0, ncor = 0;

  if (pbits < 31) {
    int shift = 31 - pbits;
    // ONE streaming pass: above-prefix keys accumulate; in-prefix -> LDS cand
#pragma unroll
    for (int half = 0; half < 2; ++half) {
      uint4 v[8];
#pragma unroll
      for (int j = 0; j < 8; ++j)
        v[j] = k4[base4 + tid + (half * 8 + j) * 1024];
#pragma unroll
      for (int j = 0; j < 8; ++j) {
        unsigned int w4[4] = {v[j].x, v[j].y, v[j].z, v[j].w};
#pragma unroll
        for (int e = 0; e < 4; ++e) {
          unsigned int key = w4[e];
          unsigned int k31 = key & 0x7FFFFFFFu;
          unsigned int vp = k31 >> shift;
          if (vp > prefix) {
            cls += __uint_as_float(k31);
            ncnt += 1;
            ncor += (int)((key >> 31) ^ 1u);
          } else if (vp == prefix) {
            unsigned int idx = atomicAdd(&s_ccnt, 1u);
            if (idx < CAP) cand[idx] = key;
          }
        }
      }
    }
    __syncthreads();
    unsigned int ccnt = s_ccnt;

    // in-LDS radix select over the remaining bits among candidates
    while (pbits < 31) {
      int nb = 31 - pbits;
      if (nb > 10) nb = 10;
      int shN = 31 - pbits, sh2 = 31 - pbits - nb;
      unsigned int msk = (1u << nb) - 1u;
      hist[tid] = 0u;
      __syncthreads();
      for (unsigned int i = tid; i < ccnt; i += 1024) {
        unsigned int k31 = cand[i] & 0x7FFFFFFFu;
        if ((k31 >> shN) == prefix)
          atomicAdd(&hist[(k31 >> sh2) & msk], 1u);
      }
      __syncthreads();
      p = pickB(hist, 1 << nb, r, s_wsum, &s_bin, &s_kr);
      prefix = (prefix << nb) | p.x;
      r = (int)p.y;
      pbits += nb;
      __syncthreads();
    }
    unsigned int thr = prefix;
    int need = r;
    for (unsigned int i = tid; i < ccnt; i += 1024) {
      unsigned int key = cand[i];
      unsigned int k31 = key & 0x7FFFFFFFu;
      bool s = false;
      if (k31 > thr) {
        s = true;
      } else if (k31 == thr) {
        unsigned int ord = atomicAdd(&s_eq, 1u);
        if ((int)ord < need) s = true;
      }
      if (s) {
        cls += __uint_as_float(k31);
        ncnt += 1;
        ncor += (int)((key >> 31) ^ 1u);
      }
    }
  } else {
    // degenerate: prefix is the full 31-bit threshold; stream-select ties
    unsigned int thr = prefix;
    int need = r;
    for (int j = 0; j < 16; ++j) {
      uint4 v = k4[base4 + tid + j * 1024];
      unsigned int w4[4] = {v.x, v.y, v.z, v.w};
#pragma unroll
      for (int e = 0; e < 4; ++e) {
        unsigned int key = w4[e];
        unsigned int k31 = key & 0x7FFFFFFFu;
        bool s = false;
        if (k31 > thr) {
          s = true;
        } else if (k31 == thr) {
          unsigned int ord = atomicAdd(&s_eq, 1u);
          if ((int)ord < need) s = true;
        }
        if (s) {
          cls += __uint_as_float(k31);
          ncnt += 1;
          ncor += (int)((key >> 31) ^ 1u);
        }
      }
    }
  }

  // block-reduce negative stats -> device atomics
  {
    float v = cls;
#pragma unroll
    for (int o = 32; o > 0; o >>= 1) v += __shfl_down(v, o, 64);
    if (lane == 0) s_nf[wv] = v;
  }
  {
    int v = ncnt;
#pragma unroll
    for (int o = 32; o > 0; o >>= 1) v += __shfl_down(v, o, 64);
    if (lane == 0) s_ni[0][wv] = v;
  }
  {
    int v = ncor;
#pragma unroll
    for (int o = 32; o > 0; o >>= 1) v += __shfl_down(v, o, 64);
    if (lane == 0) s_ni[1][wv] = v;
  }
  __syncthreads();
  if (tid == 0) {
    float C = 0;
    int NC = 0, COR = 0;
    for (int w2 = 0; w2 < 16; ++w2) {
      C += s_nf[w2];
      NC += s_ni[0][w2];
      COR += s_ni[1][w2];
    }
    atomicAdd(&acc->f_clsn, C);
    atomicAdd(&acc->i_ntot, (unsigned int)NC);
    atomicAdd(&acc->i_ncor, (unsigned int)COR);
  }

  // last-block-done final reduction
  __threadfence();
  if (tid == 0) {
    unsigned int old = __hip_atomic_fetch_add(&acc->done, 1u, __ATOMIC_ACQ_REL,
                                              __HIP_MEMORY_SCOPE_AGENT);
    s_lastf = (old == (unsigned int)(gridDim.x - 1)) ? 1u : 0u;
  }
  __syncthreads();
  if (s_lastf) {
    __threadfence();
    float fv[5];
    int iv[2];
    fv[0] = acc->f_loc[tid];
    fv[1] = acc->f_clsp[tid];
    fv[2] = acc->f_perr[tid];
    fv[3] = acc->f_se0[tid];
    fv[4] = acc->f_se1[tid];
    iv[0] = acc->i_pcor[tid];
    iv[1] = acc->i_pcnt[tid];
#pragma unroll
    for (int q = 0; q < 5; ++q) {
      float v = fv[q];
#pragma unroll
      for (int o = 32; o > 0; o >>= 1) v += __shfl_down(v, o, 64);
      if (lane == 0) s_rf[q][wv] = v;
    }
#pragma unroll
    for (int q = 0; q < 2; ++q) {
      int v = iv[q];
#pragma unroll
      for (int o = 32; o > 0; o >>= 1) v += __shfl_down(v, o, 64);
      if (lane == 0) s_ri[q][wv] = v;
    }
    __syncthreads();
    if (tid == 0) {
      float T[5] = {0, 0, 0, 0, 0};
      int TI[2] = {0, 0};
      for (int w2 = 0; w2 < 16; ++w2) {
        T[0] += s_rf[0][w2]; T[1] += s_rf[1][w2]; T[2] += s_rf[2][w2];
        T[3] += s_rf[3][w2]; T[4] += s_rf[4][w2];
        TI[0] += s_ri[0][w2]; TI[1] += s_ri[1][w2];
      }
      float clsn = __hip_atomic_load(&acc->f_clsn, __ATOMIC_RELAXED,
                                     __HIP_MEMORY_SCOPE_AGENT);
      unsigned int ntot = __hip_atomic_load(&acc->i_ntot, __ATOMIC_RELAXED,
                                            __HIP_MEMORY_SCOPE_AGENT);
      unsigned int ncr = __hip_atomic_load(&acc->i_ncor, __ATOMIC_RELAXED,
                                           __HIP_MEMORY_SCOPE_AGENT);
      float N = (float)TI[1];
      float Nf = fmaxf(N, 1.f);
      out[0] = T[0] / (Nf * 4.f);
      float wsum = N + (float)ntot * (1.f / 3.f);
      out[1] = (T[1] + clsn * (1.f / 3.f)) / wsum;
      out[2] = (float)TI[0] / fmaxf(N, 1.f);
      out[3] = (float)ncr / fmaxf((float)ntot, 1.f);
      out[4] = T[2] / Nf;
      out[5] = T[3] / Nf * 255.f;
      out[6] = T[4] / Nf * 255.f;
      out[7] = N;
    }
  }
}

extern "C" void kernel_launch(void* const* d_in, const int* in_sizes, int n_in,
                              void* d_out, int out_size, void* d_ws,
                              size_t ws_size, hipStream_t stream) {
  (void)n_in; (void)out_size; (void)ws_size;
  const float* loc = (const float*)d_in[0];
  const float* conf = (const float*)d_in[1];
  const float* gt = (const float*)d_in[2];
  const float* anchors = (const float*)d_in[3];
  int B = in_sizes[2] / 4;  // 64
  int A = in_sizes[3] / 4;  // 65536
  float* out = (float*)d_out;

  int spr = A / 4096;  // 16 blocks per row

  char* w = (char*)d_ws;
  Accum* acc = (Accum*)w;
  size_t off = (sizeof(Accum) + 255) & ~(size_t)255;
  unsigned int* g1 = (unsigned int*)(w + off);
  off += (size_t)B * spr * NB1 * 4;
  off = (off + 255) & ~(size_t)255;
  unsigned int* keys = (unsigned int*)(w + off);

  dim3 grid(spr, B);
  k_main<<<grid, 256, 0, stream>>>(loc, conf, gt, anchors, acc, g1, keys, A);
  k_select<<<B, 1024, 0, stream>>>(keys, g1, acc, out, A, spr);
}